// Round 3
// baseline (1533.542 us; speedup 1.0000x reference)
//
#include <hip/hip_runtime.h>
#include <hip/hip_bf16.h>
#include <math.h>

typedef __bf16 bf16x8 __attribute__((ext_vector_type(8)));
typedef float f32x4 __attribute__((ext_vector_type(4)));

constexpr int HID = 1024;
constexpr int NHEAD = 16;
constexpr int NKV = 4;
constexpr int HDIM = 64;
constexpr int NEXP = 16;
constexpr int FFD = 1024;
constexpr int NB = 2;
constexpr int SEQ = 1024;
constexpr int TOK = NB * SEQ;
constexpr int QKV_N = NHEAD * HDIM + 2 * NKV * HDIM;  // 1536
constexpr float RMS_EPS = 1e-6f;
constexpr int LDP = 40;          // padded LDS row stride (bf16 elems) -> 2-way-free banks
constexpr int PL = 64 * LDP;     // one 64-row LDS plane
constexpr int HCH = 8;           // heads per attention chunk

// x = h1 + h2 + h3 with h2 ~ eps*x, h3 ~ eps^2*x (residual subs exact).
__device__ __forceinline__ void split3(float x, __bf16& h1, __bf16& h2, __bf16& h3) {
  h1 = (__bf16)x; float r1 = x - (float)h1;
  h2 = (__bf16)r1; float r2 = r1 - (float)h2;
  h3 = (__bf16)r2;
}

// 6-combination triple-split MFMA step: error ~eps^3 (fp32-grade).
__device__ __forceinline__ void mfma_step6(const __bf16* sm, int wr, int wc,
                                           int lm, int lq, f32x4 (&acc)[2][2]) {
  int ao0 = (wr + lm) * LDP + lq * 8, ao1 = (wr + 16 + lm) * LDP + lq * 8;
  int bo0 = (wc + lm) * LDP + lq * 8, bo1 = (wc + 16 + lm) * LDP + lq * 8;
  bf16x8 a10 = *(const bf16x8*)(sm + ao0),          a11 = *(const bf16x8*)(sm + ao1);
  bf16x8 a20 = *(const bf16x8*)(sm + PL + ao0),     a21 = *(const bf16x8*)(sm + PL + ao1);
  bf16x8 a30 = *(const bf16x8*)(sm + 2 * PL + ao0), a31 = *(const bf16x8*)(sm + 2 * PL + ao1);
  bf16x8 b10 = *(const bf16x8*)(sm + 3 * PL + bo0), b11 = *(const bf16x8*)(sm + 3 * PL + bo1);
  bf16x8 b20 = *(const bf16x8*)(sm + 4 * PL + bo0), b21 = *(const bf16x8*)(sm + 4 * PL + bo1);
  bf16x8 b30 = *(const bf16x8*)(sm + 5 * PL + bo0), b31 = *(const bf16x8*)(sm + 5 * PL + bo1);
#define MF(A, B, i, j) acc[i][j] = __builtin_amdgcn_mfma_f32_16x16x32_bf16(A, B, acc[i][j], 0, 0, 0)
  MF(a10, b10, 0, 0); MF(a10, b11, 0, 1); MF(a11, b10, 1, 0); MF(a11, b11, 1, 1);
  MF(a10, b20, 0, 0); MF(a10, b21, 0, 1); MF(a11, b20, 1, 0); MF(a11, b21, 1, 1);
  MF(a20, b10, 0, 0); MF(a20, b11, 0, 1); MF(a21, b10, 1, 0); MF(a21, b11, 1, 1);
  MF(a20, b20, 0, 0); MF(a20, b21, 0, 1); MF(a21, b20, 1, 0); MF(a21, b21, 1, 1);
  MF(a10, b30, 0, 0); MF(a10, b31, 0, 1); MF(a11, b30, 1, 0); MF(a11, b31, 1, 1);
  MF(a30, b10, 0, 0); MF(a30, b11, 0, 1); MF(a31, b10, 1, 0); MF(a31, b11, 1, 1);
#undef MF
}

__device__ __forceinline__ void cvt8(__bf16* dst, float4 f0, float4 f1) {
  __bf16 tmp[8] __attribute__((aligned(16))) = {
      (__bf16)f0.x, (__bf16)f0.y, (__bf16)f0.z, (__bf16)f0.w,
      (__bf16)f1.x, (__bf16)f1.y, (__bf16)f1.z, (__bf16)f1.w};
  *(int4*)dst = *(const int4*)tmp;
}

// ---------------- pre/post small kernels ----------------

__global__ __launch_bounds__(256) void split3_kernel(
    const float* __restrict__ src, __bf16* __restrict__ p1,
    __bf16* __restrict__ p2, __bf16* __restrict__ p3, int n) {
  int i = (blockIdx.x * 256 + threadIdx.x) * 4;
  if (i >= n) return;
  float4 v = *(const float4*)(src + i);
  __bf16 t1[4] __attribute__((aligned(8))), t2[4] __attribute__((aligned(8))),
      t3[4] __attribute__((aligned(8)));
  split3(v.x, t1[0], t2[0], t3[0]);
  split3(v.y, t1[1], t2[1], t3[1]);
  split3(v.z, t1[2], t2[2], t3[2]);
  split3(v.w, t1[3], t2[3], t3[3]);
  *(int2*)(p1 + i) = *(const int2*)t1;
  *(int2*)(p2 + i) = *(const int2*)t2;
  *(int2*)(p3 + i) = *(const int2*)t3;
}

__global__ __launch_bounds__(256) void rmsnorm_split3_kernel(
    const float* __restrict__ x, const float* __restrict__ w,
    __bf16* __restrict__ p1, __bf16* __restrict__ p2, __bf16* __restrict__ p3) {
  int row = blockIdx.x;
  const float* xr = x + (size_t)row * HID;
  float4 v = ((const float4*)xr)[threadIdx.x];
  float ss = v.x * v.x + v.y * v.y + v.z * v.z + v.w * v.w;
  for (int off = 32; off; off >>= 1) ss += __shfl_xor(ss, off);
  __shared__ float red[4];
  int lane = threadIdx.x & 63, wid = threadIdx.x >> 6;
  if (lane == 0) red[wid] = ss;
  __syncthreads();
  float tot = red[0] + red[1] + red[2] + red[3];
  float scale = rsqrtf(tot / (float)HID + RMS_EPS);
  float4 wv = ((const float4*)w)[threadIdx.x];
  float o[4] = {v.x * scale * wv.x, v.y * scale * wv.y,
                v.z * scale * wv.z, v.w * scale * wv.w};
  __bf16 t1[4] __attribute__((aligned(8))), t2[4] __attribute__((aligned(8))),
      t3[4] __attribute__((aligned(8)));
#pragma unroll
  for (int i = 0; i < 4; i++) split3(o[i], t1[i], t2[i], t3[i]);
  size_t idx = (size_t)row * HID + threadIdx.x * 4;
  *(int2*)(p1 + idx) = *(const int2*)t1;
  *(int2*)(p2 + idx) = *(const int2*)t2;
  *(int2*)(p3 + idx) = *(const int2*)t3;
}

__global__ __launch_bounds__(256) void rmsnorm_dual_kernel(
    const float* __restrict__ x, const float* __restrict__ w,
    float* __restrict__ outf, __bf16* __restrict__ outb) {
  int row = blockIdx.x;
  const float* xr = x + (size_t)row * HID;
  float4 v = ((const float4*)xr)[threadIdx.x];
  float ss = v.x * v.x + v.y * v.y + v.z * v.z + v.w * v.w;
  for (int off = 32; off; off >>= 1) ss += __shfl_xor(ss, off);
  __shared__ float red[4];
  int lane = threadIdx.x & 63, wid = threadIdx.x >> 6;
  if (lane == 0) red[wid] = ss;
  __syncthreads();
  float tot = red[0] + red[1] + red[2] + red[3];
  float scale = rsqrtf(tot / (float)HID + RMS_EPS);
  float4 wv = ((const float4*)w)[threadIdx.x];
  float o[4] = {v.x * scale * wv.x, v.y * scale * wv.y,
                v.z * scale * wv.z, v.w * scale * wv.w};
  size_t idx = (size_t)row * HID + threadIdx.x * 4;
  *(float4*)(outf + idx) = *(const float4*)o;
  __bf16 tb[4] __attribute__((aligned(8)));
#pragma unroll
  for (int i = 0; i < 4; i++) tb[i] = (__bf16)o[i];
  *(int2*)(outb + idx) = *(const int2*)tb;
}

__global__ __launch_bounds__(256) void rope_split_kernel(
    const float* __restrict__ qkv, const int* __restrict__ pos_ids,
    const float* __restrict__ qn_w, const float* __restrict__ kn_w,
    __bf16* __restrict__ qp1, __bf16* __restrict__ qp2, __bf16* __restrict__ qp3,
    __bf16* __restrict__ kp1, __bf16* __restrict__ kp2, __bf16* __restrict__ kp3,
    __bf16* __restrict__ vp1, __bf16* __restrict__ vp2, __bf16* __restrict__ vp3) {
  int t = blockIdx.x;
  int b = t >> 10, s = t & 1023;
  int lane = threadIdx.x & 63, w = threadIdx.x >> 6;
  float pos = (float)pos_ids[t];
  int fi = lane & 31;
  float inv = powf(10000.0f, -((float)(2 * fi)) / 64.0f);
  float cs = cosf(pos * inv), sn = sinf(pos * inv);
  for (int i = 0; i < 6; i++) {
    int hh = w + 4 * i;  // 0-15 q heads, 16-19 k heads, 20-23 v heads
    float val = qkv[(size_t)t * QKV_N + hh * 64 + lane];
    __bf16 h1, h2, h3;
    if (hh < 20) {
      float ss = val * val;
      for (int off = 32; off; off >>= 1) ss += __shfl_xor(ss, off);
      float scale = rsqrtf(ss / 64.0f + RMS_EPS);
      float wgt = (hh < 16) ? qn_w[lane] : kn_w[lane];
      val = val * scale * wgt;
      float partner = __shfl_xor(val, 32);
      float rot = (lane < 32) ? -partner : partner;
      val = val * cs + rot * sn;
      split3(val, h1, h2, h3);
      if (hh < 16) {
        size_t idx = (((size_t)b * NHEAD + hh) * SEQ + s) * HDIM + lane;
        qp1[idx] = h1; qp2[idx] = h2; qp3[idx] = h3;
      } else {
        size_t idx = (((size_t)b * NKV + (hh - 16)) * SEQ + s) * HDIM + lane;
        kp1[idx] = h1; kp2[idx] = h2; kp3[idx] = h3;
      }
    } else {
      split3(val, h1, h2, h3);
      size_t idx = (((size_t)b * NKV + (hh - 20)) * HDIM + lane) * SEQ + s;
      vp1[idx] = h1; vp2[idx] = h2; vp3[idx] = h3;
    }
  }
}

__global__ __launch_bounds__(256) void softmax3_kernel(
    __bf16* __restrict__ p1, __bf16* __restrict__ p2, __bf16* __restrict__ p3) {
  size_t roff = (size_t)blockIdx.x * SEQ;
  int tid = threadIdx.x;
  __bf16 t1[4] __attribute__((aligned(8))), t2[4] __attribute__((aligned(8))),
      t3[4] __attribute__((aligned(8)));
  *(int2*)t1 = *(const int2*)(p1 + roff + tid * 4);
  *(int2*)t2 = *(const int2*)(p2 + roff + tid * 4);
  *(int2*)t3 = *(const int2*)(p3 + roff + tid * 4);
  float v[4];
#pragma unroll
  for (int i = 0; i < 4; i++) v[i] = (float)t1[i] + (float)t2[i] + (float)t3[i];
  float mx = fmaxf(fmaxf(v[0], v[1]), fmaxf(v[2], v[3]));
  for (int off = 32; off; off >>= 1) mx = fmaxf(mx, __shfl_xor(mx, off));
  __shared__ float red[4], red2[4];
  int lane = tid & 63, wid = tid >> 6;
  if (lane == 0) red[wid] = mx;
  __syncthreads();
  mx = fmaxf(fmaxf(red[0], red[1]), fmaxf(red[2], red[3]));
  float e[4], sum = 0.f;
#pragma unroll
  for (int i = 0; i < 4; i++) { e[i] = expf(v[i] - mx); sum += e[i]; }
  for (int off = 32; off; off >>= 1) sum += __shfl_xor(sum, off);
  if (lane == 0) red2[wid] = sum;
  __syncthreads();
  sum = red2[0] + red2[1] + red2[2] + red2[3];
  float invs = 1.0f / sum;
#pragma unroll
  for (int i = 0; i < 4; i++) split3(e[i] * invs, t1[i], t2[i], t3[i]);
  *(int2*)(p1 + roff + tid * 4) = *(const int2*)t1;
  *(int2*)(p2 + roff + tid * 4) = *(const int2*)t2;
  *(int2*)(p3 + roff + tid * 4) = *(const int2*)t3;
}

// ------------- triple-split GEMMs (64x64 tile, BK=32, reg-prefetch pipeline) -------------

__global__ __launch_bounds__(256) void gemm_qkv6(
    const __bf16* __restrict__ a1, const __bf16* __restrict__ a2, const __bf16* __restrict__ a3,
    const __bf16* __restrict__ b1, const __bf16* __restrict__ b2, const __bf16* __restrict__ b3,
    float* __restrict__ qkv) {
  int m0 = blockIdx.x * 64, n0 = blockIdx.y * 64;
  __shared__ __bf16 sm[6 * PL];
  int tid = threadIdx.x, r = tid >> 2, c8 = (tid & 3) * 8;
  size_t aoff = (size_t)(m0 + r) * HID + c8, boff = (size_t)(n0 + r) * HID + c8;
  f32x4 acc[2][2] = {};
  int lane = tid & 63, wid = tid >> 6;
  int wr = (wid >> 1) * 32, wc = (wid & 1) * 32, lq = lane >> 4, lm = lane & 15;
  int sidx = r * LDP + c8;
  int4 rg[6];
  auto preload = [&](int k0) {
    rg[0] = *(const int4*)(a1 + aoff + k0);
    rg[1] = *(const int4*)(a2 + aoff + k0);
    rg[2] = *(const int4*)(a3 + aoff + k0);
    rg[3] = *(const int4*)(b1 + boff + k0);
    rg[4] = *(const int4*)(b2 + boff + k0);
    rg[5] = *(const int4*)(b3 + boff + k0);
  };
  preload(0);
  for (int k0 = 0; k0 < HID; k0 += 32) {
#pragma unroll
    for (int p = 0; p < 6; p++) *(int4*)&sm[p * PL + sidx] = rg[p];
    __syncthreads();
    if (k0 + 32 < HID) preload(k0 + 32);
    mfma_step6(sm, wr, wc, lm, lq, acc);
    __syncthreads();
  }
#pragma unroll
  for (int mt = 0; mt < 2; mt++)
#pragma unroll
    for (int nt = 0; nt < 2; nt++)
#pragma unroll
      for (int i = 0; i < 4; i++) {
        int gm = m0 + wr + mt * 16 + lq * 4 + i;
        int gc = n0 + wc + nt * 16 + lm;
        qkv[(size_t)gm * QKV_N + gc] = acc[mt][nt][i];
      }
}

__global__ __launch_bounds__(256) void gemm_scores6(
    const __bf16* __restrict__ qp1, const __bf16* __restrict__ qp2, const __bf16* __restrict__ qp3,
    const __bf16* __restrict__ kp1, const __bf16* __restrict__ kp2, const __bf16* __restrict__ kp3,
    __bf16* __restrict__ s1, __bf16* __restrict__ s2, __bf16* __restrict__ s3,
    int b, int h0) {
  int hz = blockIdx.z, h = h0 + hz;
  int m0 = blockIdx.x * 64, n0 = blockIdx.y * 64;
  size_t qbase = ((size_t)(b * NHEAD + h)) * SEQ * HDIM;
  size_t kbase = ((size_t)(b * NKV + (h >> 2))) * SEQ * HDIM;
  __shared__ __bf16 sm[6 * PL];
  int tid = threadIdx.x, r = tid >> 2, c8 = (tid & 3) * 8;
  size_t aoff = qbase + (size_t)(m0 + r) * HDIM + c8;
  size_t boff = kbase + (size_t)(n0 + r) * HDIM + c8;
  f32x4 acc[2][2] = {};
  int lane = tid & 63, wid = tid >> 6;
  int wr = (wid >> 1) * 32, wc = (wid & 1) * 32, lq = lane >> 4, lm = lane & 15;
  int sidx = r * LDP + c8;
  int4 rg[6];
  auto preload = [&](int k0) {
    rg[0] = *(const int4*)(qp1 + aoff + k0);
    rg[1] = *(const int4*)(qp2 + aoff + k0);
    rg[2] = *(const int4*)(qp3 + aoff + k0);
    rg[3] = *(const int4*)(kp1 + boff + k0);
    rg[4] = *(const int4*)(kp2 + boff + k0);
    rg[5] = *(const int4*)(kp3 + boff + k0);
  };
  preload(0);
  for (int k0 = 0; k0 < HDIM; k0 += 32) {
#pragma unroll
    for (int p = 0; p < 6; p++) *(int4*)&sm[p * PL + sidx] = rg[p];
    __syncthreads();
    if (k0 + 32 < HDIM) preload(k0 + 32);
    mfma_step6(sm, wr, wc, lm, lq, acc);
    __syncthreads();
  }
#pragma unroll
  for (int mt = 0; mt < 2; mt++)
#pragma unroll
    for (int nt = 0; nt < 2; nt++)
#pragma unroll
      for (int i = 0; i < 4; i++) {
        int gm = m0 + wr + mt * 16 + lq * 4 + i;
        int gc = n0 + wc + nt * 16 + lm;
        size_t idx = ((size_t)hz * SEQ + gm) * SEQ + gc;
        __bf16 h1_, h2_, h3_;
        split3(acc[mt][nt][i] * 0.125f, h1_, h2_, h3_);
        s1[idx] = h1_; s2[idx] = h2_; s3[idx] = h3_;
      }
}

__global__ __launch_bounds__(256) void gemm_pv6(
    const __bf16* __restrict__ s1, const __bf16* __restrict__ s2, const __bf16* __restrict__ s3,
    const __bf16* __restrict__ vp1, const __bf16* __restrict__ vp2, const __bf16* __restrict__ vp3,
    __bf16* __restrict__ o1, __bf16* __restrict__ o2, __bf16* __restrict__ o3,
    int b, int h0) {
  int hz = blockIdx.z, h = h0 + hz;
  int m0 = blockIdx.x * 64;
  size_t pbase = (size_t)hz * SEQ * SEQ;
  size_t vbase = ((size_t)(b * NKV + (h >> 2))) * HDIM * SEQ;
  __shared__ __bf16 sm[6 * PL];
  int tid = threadIdx.x, r = tid >> 2, c8 = (tid & 3) * 8;
  size_t aoff = pbase + (size_t)(m0 + r) * SEQ + c8;
  size_t boff = vbase + (size_t)r * SEQ + c8;
  f32x4 acc[2][2] = {};
  int lane = tid & 63, wid = tid >> 6;
  int wr = (wid >> 1) * 32, wc = (wid & 1) * 32, lq = lane >> 4, lm = lane & 15;
  int sidx = r * LDP + c8;
  int4 rg[6];
  auto preload = [&](int k0) {
    rg[0] = *(const int4*)(s1 + aoff + k0);
    rg[1] = *(const int4*)(s2 + aoff + k0);
    rg[2] = *(const int4*)(s3 + aoff + k0);
    rg[3] = *(const int4*)(vp1 + boff + k0);
    rg[4] = *(const int4*)(vp2 + boff + k0);
    rg[5] = *(const int4*)(vp3 + boff + k0);
  };
  preload(0);
  for (int k0 = 0; k0 < SEQ; k0 += 32) {
#pragma unroll
    for (int p = 0; p < 6; p++) *(int4*)&sm[p * PL + sidx] = rg[p];
    __syncthreads();
    if (k0 + 32 < SEQ) preload(k0 + 32);
    mfma_step6(sm, wr, wc, lm, lq, acc);
    __syncthreads();
  }
#pragma unroll
  for (int mt = 0; mt < 2; mt++)
#pragma unroll
    for (int nt = 0; nt < 2; nt++)
#pragma unroll
      for (int i = 0; i < 4; i++) {
        int gm = m0 + wr + mt * 16 + lq * 4 + i;
        int gc = wc + nt * 16 + lm;
        size_t idx = ((size_t)(b * SEQ + gm)) * HID + h * 64 + gc;
        __bf16 h1_, h2_, h3_;
        split3(acc[mt][nt][i], h1_, h2_, h3_);
        o1[idx] = h1_; o2[idx] = h2_; o3[idx] = h3_;
      }
}

__global__ __launch_bounds__(256) void gemm_oproj6(
    const __bf16* __restrict__ a1, const __bf16* __restrict__ a2, const __bf16* __restrict__ a3,
    const __bf16* __restrict__ b1, const __bf16* __restrict__ b2, const __bf16* __restrict__ b3,
    const float* __restrict__ hidden, float* __restrict__ x1, float* __restrict__ outp) {
  int m0 = blockIdx.x * 64, n0 = blockIdx.y * 64;
  __shared__ __bf16 sm[6 * PL];
  int tid = threadIdx.x, r = tid >> 2, c8 = (tid & 3) * 8;
  size_t aoff = (size_t)(m0 + r) * HID + c8, boff = (size_t)(n0 + r) * HID + c8;
  f32x4 acc[2][2] = {};
  int lane = tid & 63, wid = tid >> 6;
  int wr = (wid >> 1) * 32, wc = (wid & 1) * 32, lq = lane >> 4, lm = lane & 15;
  int sidx = r * LDP + c8;
  int4 rg[6];
  auto preload = [&](int k0) {
    rg[0] = *(const int4*)(a1 + aoff + k0);
    rg[1] = *(const int4*)(a2 + aoff + k0);
    rg[2] = *(const int4*)(a3 + aoff + k0);
    rg[3] = *(const int4*)(b1 + boff + k0);
    rg[4] = *(const int4*)(b2 + boff + k0);
    rg[5] = *(const int4*)(b3 + boff + k0);
  };
  preload(0);
  for (int k0 = 0; k0 < HID; k0 += 32) {
#pragma unroll
    for (int p = 0; p < 6; p++) *(int4*)&sm[p * PL + sidx] = rg[p];
    __syncthreads();
    if (k0 + 32 < HID) preload(k0 + 32);
    mfma_step6(sm, wr, wc, lm, lq, acc);
    __syncthreads();
  }
#pragma unroll
  for (int mt = 0; mt < 2; mt++)
#pragma unroll
    for (int nt = 0; nt < 2; nt++)
#pragma unroll
      for (int i = 0; i < 4; i++) {
        int gm = m0 + wr + mt * 16 + lq * 4 + i;
        int gc = n0 + wc + nt * 16 + lm;
        size_t idx = (size_t)gm * HID + gc;
        float val = hidden[idx] + acc[mt][nt][i];
        x1[idx] = val;
        outp[idx] = val;
      }
}

// ---------------- MoE ----------------

__global__ void zero_cnt_kernel(int* cnt) {
  if (threadIdx.x < NEXP) cnt[threadIdx.x] = 0;
}

__global__ __launch_bounds__(64) void gating_kernel(
    const float* __restrict__ h2f, const float* __restrict__ gw,
    float* __restrict__ logits_out, int* __restrict__ cnt,
    int* __restrict__ list, float* __restrict__ wt) {
  int t = blockIdx.x;
  int lane = threadIdx.x;
  const float* xr = h2f + (size_t)t * HID;
  float part[NEXP] = {};
  for (int k = lane; k < HID; k += 64) {
    float xv = xr[k];
#pragma unroll
    for (int e = 0; e < NEXP; e++) part[e] += xv * gw[e * HID + k];
  }
#pragma unroll
  for (int e = 0; e < NEXP; e++)
    for (int off = 32; off; off >>= 1) part[e] += __shfl_xor(part[e], off);
  if (lane < NEXP) logits_out[(size_t)t * NEXP + lane] = part[lane];
  float mx = part[0];
#pragma unroll
  for (int e = 1; e < NEXP; e++) mx = fmaxf(mx, part[e]);
  float pe[NEXP];
#pragma unroll
  for (int e = 0; e < NEXP; e++) pe[e] = expf(part[e] - mx);
  int e0 = 0; float p0 = pe[0];
#pragma unroll
  for (int e = 1; e < NEXP; e++) if (pe[e] > p0) { p0 = pe[e]; e0 = e; }
  int e1 = -1; float p1 = -1.f;
#pragma unroll
  for (int e = 0; e < NEXP; e++) if (e != e0 && pe[e] > p1) { p1 = pe[e]; e1 = e; }
  float wsum = p0 + p1;
  if (lane == 0) {
    int pos0 = atomicAdd(&cnt[e0], 1);
    list[e0 * TOK + pos0] = t;
    wt[e0 * TOK + pos0] = p0 / wsum;
    int pos1 = atomicAdd(&cnt[e1], 1);
    list[e1 * TOK + pos1] = t;
    wt[e1 * TOK + pos1] = p1 / wsum;
  }
}

__global__ void scan_kernel(const int* __restrict__ cnt, int* __restrict__ base) {
  if (threadIdx.x == 0 && blockIdx.x == 0) {
    int acc = 0;
    for (int e = 0; e < NEXP; e++) { base[e] = acc; acc += cnt[e]; }
    base[NEXP] = acc;
  }
}

// fused gate+up GEMM, 128(M tokens) x 64(F) tile, BK=32, reg-prefetch pipeline.
// grid (TOK/128, FFD/64, NEXP), block 256 (4 waves in 2x2; wave = 64x32).
__global__ __launch_bounds__(256) void gemm_gateup2(
    const __bf16* __restrict__ h2, const float* __restrict__ w_gate,
    const float* __restrict__ w_up, const int* __restrict__ cnt,
    const int* __restrict__ base, const int* __restrict__ list,
    __bf16* __restrict__ aws) {
  int e = blockIdx.z;
  int ce = cnt[e];
  int m0 = blockIdx.x * 128;
  if (m0 >= ce) return;
  int n0 = blockIdx.y * 64;
  int be = base[e];
  __shared__ __bf16 As[128 * LDP], Bg[64 * LDP], Bu[64 * LDP];
  int tid = threadIdx.x;
  // A staging: 128 rows x 32 cols bf16; 2 threads/row, 16 elems (2 int4) each.
  int ar = tid >> 1, aq = (tid & 1) * 16;
  int ridx = m0 + ar; if (ridx >= ce) ridx = ce - 1;
  const __bf16* arow = h2 + (size_t)list[e * TOK + ridx] * HID;
  // B staging: 64 rows x 32 cols fp32->bf16; 4 threads/row, 8 floats each.
  int br = tid >> 2, bc = (tid & 3) * 8;
  const float* bgrow = w_gate + ((size_t)e * FFD + n0 + br) * HID;
  const float* burow = w_up + ((size_t)e * FFD + n0 + br) * HID;
  int lane = tid & 63, wid = tid >> 6;
  int wr = (wid >> 1) * 64, wc = (wid & 1) * 32, lq = lane >> 4, lm = lane & 15;
  f32x4 ag[4][2] = {}, au[4][2] = {};
  int4 ra0, ra1; float4 rg0, rg1, ru0, ru1;
  auto preload = [&](int k0) {
    ra0 = *(const int4*)(arow + k0 + aq);
    ra1 = *(const int4*)(arow + k0 + aq + 8);
    rg0 = *(const float4*)(bgrow + k0 + bc);
    rg1 = *(const float4*)(bgrow + k0 + bc + 4);
    ru0 = *(const float4*)(burow + k0 + bc);
    ru1 = *(const float4*)(burow + k0 + bc + 4);
  };
  preload(0);
  for (int k0 = 0; k0 < HID; k0 += 32) {
    *(int4*)&As[ar * LDP + aq] = ra0;
    *(int4*)&As[ar * LDP + aq + 8] = ra1;
    cvt8(&Bg[br * LDP + bc], rg0, rg1);
    cvt8(&Bu[br * LDP + bc], ru0, ru1);
    __syncthreads();
    if (k0 + 32 < HID) preload(k0 + 32);
    bf16x8 af[4], gf[2], uf[2];
#pragma unroll
    for (int mt = 0; mt < 4; mt++)
      af[mt] = *(const bf16x8*)(As + (wr + mt * 16 + lm) * LDP + lq * 8);
#pragma unroll
    for (int nt = 0; nt < 2; nt++) {
      gf[nt] = *(const bf16x8*)(Bg + (wc + nt * 16 + lm) * LDP + lq * 8);
      uf[nt] = *(const bf16x8*)(Bu + (wc + nt * 16 + lm) * LDP + lq * 8);
    }
#pragma unroll
    for (int mt = 0; mt < 4; mt++)
#pragma unroll
      for (int nt = 0; nt < 2; nt++) {
        ag[mt][nt] = __builtin_amdgcn_mfma_f32_16x16x32_bf16(af[mt], gf[nt], ag[mt][nt], 0, 0, 0);
        au[mt][nt] = __builtin_amdgcn_mfma_f32_16x16x32_bf16(af[mt], uf[nt], au[mt][nt], 0, 0, 0);
      }
    __syncthreads();
  }
#pragma unroll
  for (int mt = 0; mt < 4; mt++)
#pragma unroll
    for (int nt = 0; nt < 2; nt++)
#pragma unroll
      for (int i = 0; i < 4; i++) {
        int lrow = m0 + wr + mt * 16 + lq * 4 + i;
        if (lrow < ce) {
          int gc = n0 + wc + nt * 16 + lm;
          float g = ag[mt][nt][i], u = au[mt][nt][i];
          float a = g / (1.0f + expf(-g)) * u;
          aws[((size_t)(be + lrow)) * FFD + gc] = (__bf16)a;
        }
      }
}

// down GEMM, 128 x 64 tile, BK=32, reg-prefetch; weighted atomic scatter.
// grid (TOK/128, HID/64, NEXP), block 256.
__global__ __launch_bounds__(256) void gemm_down2(
    const __bf16* __restrict__ aws, const float* __restrict__ w_down,
    const int* __restrict__ cnt, const int* __restrict__ base,
    const int* __restrict__ list, const float* __restrict__ wt,
    float* __restrict__ outp) {
  int e = blockIdx.z;
  int ce = cnt[e];
  int m0 = blockIdx.x * 128;
  if (m0 >= ce) return;
  int n0 = blockIdx.y * 64;
  int be = base[e];
  __shared__ __bf16 As[128 * LDP], Bs[64 * LDP];
  int tid = threadIdx.x;
  int ar = tid >> 1, aq = (tid & 1) * 16;
  int ridx = m0 + ar; if (ridx >= ce) ridx = ce - 1;
  const __bf16* arow = aws + (size_t)(be + ridx) * FFD;
  int br = tid >> 2, bc = (tid & 3) * 8;
  const float* brow = w_down + ((size_t)e * HID + n0 + br) * FFD;
  int lane = tid & 63, wid = tid >> 6;
  int wr = (wid >> 1) * 64, wc = (wid & 1) * 32, lq = lane >> 4, lm = lane & 15;
  f32x4 acc[4][2] = {};
  int4 ra0, ra1; float4 rb0, rb1;
  auto preload = [&](int k0) {
    ra0 = *(const int4*)(arow + k0 + aq);
    ra1 = *(const int4*)(arow + k0 + aq + 8);
    rb0 = *(const float4*)(brow + k0 + bc);
    rb1 = *(const float4*)(brow + k0 + bc + 4);
  };
  preload(0);
  for (int k0 = 0; k0 < FFD; k0 += 32) {
    *(int4*)&As[ar * LDP + aq] = ra0;
    *(int4*)&As[ar * LDP + aq + 8] = ra1;
    cvt8(&Bs[br * LDP + bc], rb0, rb1);
    __syncthreads();
    if (k0 + 32 < FFD) preload(k0 + 32);
    bf16x8 af[4], bfr[2];
#pragma unroll
    for (int mt = 0; mt < 4; mt++)
      af[mt] = *(const bf16x8*)(As + (wr + mt * 16 + lm) * LDP + lq * 8);
#pragma unroll
    for (int nt = 0; nt < 2; nt++)
      bfr[nt] = *(const bf16x8*)(Bs + (wc + nt * 16 + lm) * LDP + lq * 8);
#pragma unroll
    for (int mt = 0; mt < 4; mt++)
#pragma unroll
      for (int nt = 0; nt < 2; nt++)
        acc[mt][nt] = __builtin_amdgcn_mfma_f32_16x16x32_bf16(af[mt], bfr[nt], acc[mt][nt], 0, 0, 0);
    __syncthreads();
  }
#pragma unroll
  for (int mt = 0; mt < 4; mt++)
#pragma unroll
    for (int nt = 0; nt < 2; nt++)
#pragma unroll
      for (int i = 0; i < 4; i++) {
        int lrow = m0 + wr + mt * 16 + lq * 4 + i;
        if (lrow < ce) {
          int gc = n0 + wc + nt * 16 + lm;
          int tok = list[e * TOK + lrow];
          float wgt = wt[e * TOK + lrow];
          atomicAdd(&outp[(size_t)tok * HID + gc], wgt * acc[mt][nt][i]);
        }
      }
}

// ---------------- launcher ----------------

extern "C" void kernel_launch(void* const* d_in, const int* in_sizes, int n_in,
                              void* d_out, int out_size, void* d_ws, size_t ws_size,
                              hipStream_t stream) {
  const float* hidden = (const float*)d_in[0];
  const int* pos_ids = (const int*)d_in[1];
  const float* ln1_w = (const float*)d_in[2];
  const float* ln2_w = (const float*)d_in[3];
  const float* q_w = (const float*)d_in[4];
  const float* k_w = (const float*)d_in[5];
  const float* v_w = (const float*)d_in[6];
  const float* o_w = (const float*)d_in[7];
  const float* qn_w = (const float*)d_in[8];
  const float* kn_w = (const float*)d_in[9];
  const float* gate_w = (const float*)d_in[10];
  const float* w_gate = (const float*)d_in[11];
  const float* w_up = (const float*)d_in[12];
  const float* w_down = (const float*)d_in[13];
  float* outp = (float*)d_out;
  float* logits_out = outp + (size_t)TOK * HID;

  char* ws = (char*)d_ws;
  size_t off = 0;
  auto alloc = [&](size_t bytes) {
    void* p = ws + off;
    off += (bytes + 255) & ~(size_t)255;
    return p;
  };
  const size_t NWQ = (size_t)QKV_N * HID, NOW = (size_t)HID * HID;
  __bf16* wqp1 = (__bf16*)alloc(NWQ * 2); __bf16* wqp2 = (__bf16*)alloc(NWQ * 2);
  __bf16* wqp3 = (__bf16*)alloc(NWQ * 2);
  __bf16* owp1 = (__bf16*)alloc(NOW * 2); __bf16* owp2 = (__bf16*)alloc(NOW * 2);
  __bf16* owp3 = (__bf16*)alloc(NOW * 2);
  const size_t NH1 = (size_t)TOK * HID;
  __bf16* h1p1 = (__bf16*)alloc(NH1 * 2); __bf16* h1p2 = (__bf16*)alloc(NH1 * 2);
  __bf16* h1p3 = (__bf16*)alloc(NH1 * 2);
  float* qkvf = (float*)alloc((size_t)TOK * QKV_N * 4);
  const size_t NQ = (size_t)NB * NHEAD * SEQ * HDIM, NK = (size_t)NB * NKV * SEQ * HDIM;
  __bf16* qp1 = (__bf16*)alloc(NQ * 2); __bf16* qp2 = (__bf16*)alloc(NQ * 2);
  __bf16* qp3 = (__bf16*)alloc(NQ * 2);
  __bf16* kp1 = (__bf16*)alloc(NK * 2); __bf16* kp2 = (__bf16*)alloc(NK * 2);
  __bf16* kp3 = (__bf16*)alloc(NK * 2);
  __bf16* vp1 = (__bf16*)alloc(NK * 2); __bf16* vp2 = (__bf16*)alloc(NK * 2);
  __bf16* vp3 = (__bf16*)alloc(NK * 2);
  const size_t NP = (size_t)HCH * SEQ * SEQ;
  __bf16* sp1 = (__bf16*)alloc(NP * 2); __bf16* sp2 = (__bf16*)alloc(NP * 2);
  __bf16* sp3 = (__bf16*)alloc(NP * 2);
  __bf16* op1 = (__bf16*)alloc(NH1 * 2); __bf16* op2 = (__bf16*)alloc(NH1 * 2);
  __bf16* op3 = (__bf16*)alloc(NH1 * 2);
  float* x1 = (float*)alloc(NH1 * 4);
  float* h2f = (float*)alloc(NH1 * 4);
  __bf16* h2b = (__bf16*)alloc(NH1 * 2);
  int* cnt = (int*)alloc(NEXP * 4);
  int* base = (int*)alloc((NEXP + 1) * 4);
  int* list = (int*)alloc((size_t)NEXP * TOK * 4);
  float* wt = (float*)alloc((size_t)NEXP * TOK * 4);
  __bf16* aws = (__bf16*)alloc((size_t)TOK * 2 * FFD * 2);
  (void)ws_size; (void)in_sizes; (void)n_in; (void)out_size;

  // weight splits
  split3_kernel<<<1024, 256, 0, stream>>>(q_w, wqp1, wqp2, wqp3, 1024 * 1024);
  split3_kernel<<<256, 256, 0, stream>>>(k_w, wqp1 + 1024 * 1024, wqp2 + 1024 * 1024,
                                         wqp3 + 1024 * 1024, 256 * 1024);
  split3_kernel<<<256, 256, 0, stream>>>(v_w, wqp1 + 1280 * 1024, wqp2 + 1280 * 1024,
                                         wqp3 + 1280 * 1024, 256 * 1024);
  split3_kernel<<<1024, 256, 0, stream>>>(o_w, owp1, owp2, owp3, 1024 * 1024);

  // attention (fp32-grade via triple-split MFMA)
  rmsnorm_split3_kernel<<<TOK, 256, 0, stream>>>(hidden, ln1_w, h1p1, h1p2, h1p3);
  gemm_qkv6<<<dim3(TOK / 64, QKV_N / 64), 256, 0, stream>>>(
      h1p1, h1p2, h1p3, wqp1, wqp2, wqp3, qkvf);
  rope_split_kernel<<<TOK, 256, 0, stream>>>(qkvf, pos_ids, qn_w, kn_w,
                                             qp1, qp2, qp3, kp1, kp2, kp3, vp1, vp2, vp3);
  for (int b = 0; b < NB; b++)
    for (int hc = 0; hc < NHEAD / HCH; hc++) {
      int h0 = hc * HCH;
      gemm_scores6<<<dim3(SEQ / 64, SEQ / 64, HCH), 256, 0, stream>>>(
          qp1, qp2, qp3, kp1, kp2, kp3, sp1, sp2, sp3, b, h0);
      softmax3_kernel<<<HCH * SEQ, 256, 0, stream>>>(sp1, sp2, sp3);
      gemm_pv6<<<dim3(SEQ / 64, 1, HCH), 256, 0, stream>>>(
          sp1, sp2, sp3, vp1, vp2, vp3, op1, op2, op3, b, h0);
    }
  gemm_oproj6<<<dim3(TOK / 64, HID / 64), 256, 0, stream>>>(
      op1, op2, op3, owp1, owp2, owp3, hidden, x1, outp);

  // MoE
  rmsnorm_dual_kernel<<<TOK, 256, 0, stream>>>(x1, ln2_w, h2f, h2b);
  zero_cnt_kernel<<<1, 64, 0, stream>>>(cnt);
  gating_kernel<<<TOK, 64, 0, stream>>>(h2f, gate_w, logits_out, cnt, list, wt);
  scan_kernel<<<1, 1, 0, stream>>>(cnt, base);
  gemm_gateup2<<<dim3(TOK / 128, FFD / 64, NEXP), 256, 0, stream>>>(
      h2b, w_gate, w_up, cnt, base, list, aws);
  gemm_down2<<<dim3(TOK / 128, HID / 64, NEXP), 256, 0, stream>>>(
      aws, w_down, cnt, base, list, wt, outp);
}

// Round 4
// 677.822 us; speedup vs baseline: 2.2625x; 2.2625x over previous
//
#include <hip/hip_runtime.h>
#include <hip/hip_bf16.h>
#include <math.h>

typedef __bf16 bf16x8 __attribute__((ext_vector_type(8)));
typedef float f32x4 __attribute__((ext_vector_type(4)));

constexpr int HID = 1024;
constexpr int NHEAD = 16;
constexpr int NKV = 4;
constexpr int HDIM = 64;
constexpr int NEXP = 16;
constexpr int FFD = 1024;
constexpr int NB = 2;
constexpr int SEQ = 1024;
constexpr int TOK = NB * SEQ;
constexpr int QKV_N = NHEAD * HDIM + 2 * NKV * HDIM;  // 1536
constexpr float RMS_EPS = 1e-6f;
constexpr int LDP = 40;          // padded LDS row stride (bf16 elems)
constexpr int PL = 64 * LDP;     // one 64-row LDS plane

// x = h1 + h2 + h3 with h2 ~ eps*x, h3 ~ eps^2*x (residual subs exact).
__device__ __forceinline__ void split3(float x, __bf16& h1, __bf16& h2, __bf16& h3) {
  h1 = (__bf16)x; float r1 = x - (float)h1;
  h2 = (__bf16)r1; float r2 = r1 - (float)h2;
  h3 = (__bf16)r2;
}

// 6-combination triple-split MFMA step: error ~eps^3 (fp32-grade).
__device__ __forceinline__ void mfma_step6(const __bf16* sm, int wr, int wc,
                                           int lm, int lq, f32x4 (&acc)[2][2]) {
  int ao0 = (wr + lm) * LDP + lq * 8, ao1 = (wr + 16 + lm) * LDP + lq * 8;
  int bo0 = (wc + lm) * LDP + lq * 8, bo1 = (wc + 16 + lm) * LDP + lq * 8;
  bf16x8 a10 = *(const bf16x8*)(sm + ao0),          a11 = *(const bf16x8*)(sm + ao1);
  bf16x8 a20 = *(const bf16x8*)(sm + PL + ao0),     a21 = *(const bf16x8*)(sm + PL + ao1);
  bf16x8 a30 = *(const bf16x8*)(sm + 2 * PL + ao0), a31 = *(const bf16x8*)(sm + 2 * PL + ao1);
  bf16x8 b10 = *(const bf16x8*)(sm + 3 * PL + bo0), b11 = *(const bf16x8*)(sm + 3 * PL + bo1);
  bf16x8 b20 = *(const bf16x8*)(sm + 4 * PL + bo0), b21 = *(const bf16x8*)(sm + 4 * PL + bo1);
  bf16x8 b30 = *(const bf16x8*)(sm + 5 * PL + bo0), b31 = *(const bf16x8*)(sm + 5 * PL + bo1);
#define MF(A, B, i, j) acc[i][j] = __builtin_amdgcn_mfma_f32_16x16x32_bf16(A, B, acc[i][j], 0, 0, 0)
  MF(a10, b10, 0, 0); MF(a10, b11, 0, 1); MF(a11, b10, 1, 0); MF(a11, b11, 1, 1);
  MF(a10, b20, 0, 0); MF(a10, b21, 0, 1); MF(a11, b20, 1, 0); MF(a11, b21, 1, 1);
  MF(a20, b10, 0, 0); MF(a20, b11, 0, 1); MF(a21, b10, 1, 0); MF(a21, b11, 1, 1);
  MF(a20, b20, 0, 0); MF(a20, b21, 0, 1); MF(a21, b20, 1, 0); MF(a21, b21, 1, 1);
  MF(a10, b30, 0, 0); MF(a10, b31, 0, 1); MF(a11, b30, 1, 0); MF(a11, b31, 1, 1);
  MF(a30, b10, 0, 0); MF(a30, b11, 0, 1); MF(a31, b10, 1, 0); MF(a31, b11, 1, 1);
#undef MF
}

__device__ __forceinline__ void cvt8(__bf16* dst, float4 f0, float4 f1) {
  __bf16 tmp[8] __attribute__((aligned(16))) = {
      (__bf16)f0.x, (__bf16)f0.y, (__bf16)f0.z, (__bf16)f0.w,
      (__bf16)f1.x, (__bf16)f1.y, (__bf16)f1.z, (__bf16)f1.w};
  *(int4*)dst = *(const int4*)tmp;
}

// ---------------- pre/post small kernels ----------------

__global__ __launch_bounds__(256) void split3_kernel(
    const float* __restrict__ src, __bf16* __restrict__ p1,
    __bf16* __restrict__ p2, __bf16* __restrict__ p3, int n) {
  int i = (blockIdx.x * 256 + threadIdx.x) * 4;
  if (i >= n) return;
  float4 v = *(const float4*)(src + i);
  __bf16 t1[4] __attribute__((aligned(8))), t2[4] __attribute__((aligned(8))),
      t3[4] __attribute__((aligned(8)));
  split3(v.x, t1[0], t2[0], t3[0]);
  split3(v.y, t1[1], t2[1], t3[1]);
  split3(v.z, t1[2], t2[2], t3[2]);
  split3(v.w, t1[3], t2[3], t3[3]);
  *(int2*)(p1 + i) = *(const int2*)t1;
  *(int2*)(p2 + i) = *(const int2*)t2;
  *(int2*)(p3 + i) = *(const int2*)t3;
}

__global__ __launch_bounds__(256) void rmsnorm_split3_kernel(
    const float* __restrict__ x, const float* __restrict__ w,
    __bf16* __restrict__ p1, __bf16* __restrict__ p2, __bf16* __restrict__ p3) {
  int row = blockIdx.x;
  const float* xr = x + (size_t)row * HID;
  float4 v = ((const float4*)xr)[threadIdx.x];
  float ss = v.x * v.x + v.y * v.y + v.z * v.z + v.w * v.w;
  for (int off = 32; off; off >>= 1) ss += __shfl_xor(ss, off);
  __shared__ float red[4];
  int lane = threadIdx.x & 63, wid = threadIdx.x >> 6;
  if (lane == 0) red[wid] = ss;
  __syncthreads();
  float tot = red[0] + red[1] + red[2] + red[3];
  float scale = rsqrtf(tot / (float)HID + RMS_EPS);
  float4 wv = ((const float4*)w)[threadIdx.x];
  float o[4] = {v.x * scale * wv.x, v.y * scale * wv.y,
                v.z * scale * wv.z, v.w * scale * wv.w};
  __bf16 t1[4] __attribute__((aligned(8))), t2[4] __attribute__((aligned(8))),
      t3[4] __attribute__((aligned(8)));
#pragma unroll
  for (int i = 0; i < 4; i++) split3(o[i], t1[i], t2[i], t3[i]);
  size_t idx = (size_t)row * HID + threadIdx.x * 4;
  *(int2*)(p1 + idx) = *(const int2*)t1;
  *(int2*)(p2 + idx) = *(const int2*)t2;
  *(int2*)(p3 + idx) = *(const int2*)t3;
}

__global__ __launch_bounds__(256) void rmsnorm_dual_kernel(
    const float* __restrict__ x, const float* __restrict__ w,
    float* __restrict__ outf, __bf16* __restrict__ outb) {
  int row = blockIdx.x;
  const float* xr = x + (size_t)row * HID;
  float4 v = ((const float4*)xr)[threadIdx.x];
  float ss = v.x * v.x + v.y * v.y + v.z * v.z + v.w * v.w;
  for (int off = 32; off; off >>= 1) ss += __shfl_xor(ss, off);
  __shared__ float red[4];
  int lane = threadIdx.x & 63, wid = threadIdx.x >> 6;
  if (lane == 0) red[wid] = ss;
  __syncthreads();
  float tot = red[0] + red[1] + red[2] + red[3];
  float scale = rsqrtf(tot / (float)HID + RMS_EPS);
  float4 wv = ((const float4*)w)[threadIdx.x];
  float o[4] = {v.x * scale * wv.x, v.y * scale * wv.y,
                v.z * scale * wv.z, v.w * scale * wv.w};
  size_t idx = (size_t)row * HID + threadIdx.x * 4;
  *(float4*)(outf + idx) = *(const float4*)o;
  __bf16 tb[4] __attribute__((aligned(8)));
#pragma unroll
  for (int i = 0; i < 4; i++) tb[i] = (__bf16)o[i];
  *(int2*)(outb + idx) = *(const int2*)tb;
}

__global__ __launch_bounds__(256) void rope_split_kernel(
    const float* __restrict__ qkv, const int* __restrict__ pos_ids,
    const float* __restrict__ qn_w, const float* __restrict__ kn_w,
    __bf16* __restrict__ qp1, __bf16* __restrict__ qp2, __bf16* __restrict__ qp3,
    __bf16* __restrict__ kp1, __bf16* __restrict__ kp2, __bf16* __restrict__ kp3,
    __bf16* __restrict__ vp1, __bf16* __restrict__ vp2, __bf16* __restrict__ vp3) {
  int t = blockIdx.x;
  int b = t >> 10, s = t & 1023;
  int lane = threadIdx.x & 63, w = threadIdx.x >> 6;
  float pos = (float)pos_ids[t];
  int fi = lane & 31;
  float inv = powf(10000.0f, -((float)(2 * fi)) / 64.0f);
  float cs = cosf(pos * inv), sn = sinf(pos * inv);
  for (int i = 0; i < 6; i++) {
    int hh = w + 4 * i;  // 0-15 q heads, 16-19 k heads, 20-23 v heads
    float val = qkv[(size_t)t * QKV_N + hh * 64 + lane];
    __bf16 h1, h2, h3;
    if (hh < 20) {
      float ss = val * val;
      for (int off = 32; off; off >>= 1) ss += __shfl_xor(ss, off);
      float scale = rsqrtf(ss / 64.0f + RMS_EPS);
      float wgt = (hh < 16) ? qn_w[lane] : kn_w[lane];
      val = val * scale * wgt;
      float partner = __shfl_xor(val, 32);
      float rot = (lane < 32) ? -partner : partner;
      val = val * cs + rot * sn;
      split3(val, h1, h2, h3);
      if (hh < 16) {
        size_t idx = (((size_t)b * NHEAD + hh) * SEQ + s) * HDIM + lane;
        qp1[idx] = h1; qp2[idx] = h2; qp3[idx] = h3;
      } else {
        size_t idx = (((size_t)b * NKV + (hh - 16)) * SEQ + s) * HDIM + lane;
        kp1[idx] = h1; kp2[idx] = h2; kp3[idx] = h3;
      }
    } else {
      split3(val, h1, h2, h3);
      size_t idx = (((size_t)b * NKV + (hh - 20)) * HDIM + lane) * SEQ + s;
      vp1[idx] = h1; vp2[idx] = h2; vp3[idx] = h3;
    }
  }
}

__global__ __launch_bounds__(256) void softmax3_kernel(
    __bf16* __restrict__ p1, __bf16* __restrict__ p2, __bf16* __restrict__ p3) {
  size_t roff = (size_t)blockIdx.x * SEQ;
  int tid = threadIdx.x;
  __bf16 t1[4] __attribute__((aligned(8))), t2[4] __attribute__((aligned(8))),
      t3[4] __attribute__((aligned(8)));
  *(int2*)t1 = *(const int2*)(p1 + roff + tid * 4);
  *(int2*)t2 = *(const int2*)(p2 + roff + tid * 4);
  *(int2*)t3 = *(const int2*)(p3 + roff + tid * 4);
  float v[4];
#pragma unroll
  for (int i = 0; i < 4; i++) v[i] = (float)t1[i] + (float)t2[i] + (float)t3[i];
  float mx = fmaxf(fmaxf(v[0], v[1]), fmaxf(v[2], v[3]));
  for (int off = 32; off; off >>= 1) mx = fmaxf(mx, __shfl_xor(mx, off));
  __shared__ float red[4], red2[4];
  int lane = tid & 63, wid = tid >> 6;
  if (lane == 0) red[wid] = mx;
  __syncthreads();
  mx = fmaxf(fmaxf(red[0], red[1]), fmaxf(red[2], red[3]));
  float e[4], sum = 0.f;
#pragma unroll
  for (int i = 0; i < 4; i++) { e[i] = expf(v[i] - mx); sum += e[i]; }
  for (int off = 32; off; off >>= 1) sum += __shfl_xor(sum, off);
  if (lane == 0) red2[wid] = sum;
  __syncthreads();
  sum = red2[0] + red2[1] + red2[2] + red2[3];
  float invs = 1.0f / sum;
#pragma unroll
  for (int i = 0; i < 4; i++) split3(e[i] * invs, t1[i], t2[i], t3[i]);
  *(int2*)(p1 + roff + tid * 4) = *(const int2*)t1;
  *(int2*)(p2 + roff + tid * 4) = *(const int2*)t2;
  *(int2*)(p3 + roff + tid * 4) = *(const int2*)t3;
}

// ------------- triple-split GEMMs (64x64 tile, BK=32) — round-2 known-good loop -------------

__global__ __launch_bounds__(256) void gemm_qkv6(
    const __bf16* __restrict__ a1, const __bf16* __restrict__ a2, const __bf16* __restrict__ a3,
    const __bf16* __restrict__ b1, const __bf16* __restrict__ b2, const __bf16* __restrict__ b3,
    float* __restrict__ qkv) {
  int m0 = blockIdx.x * 64, n0 = blockIdx.y * 64;
  __shared__ __bf16 sm[6 * PL];
  int tid = threadIdx.x, r = tid >> 2, c8 = (tid & 3) * 8;
  size_t aoff = (size_t)(m0 + r) * HID + c8, boff = (size_t)(n0 + r) * HID + c8;
  f32x4 acc[2][2] = {};
  int lane = tid & 63, wid = tid >> 6;
  int wr = (wid >> 1) * 32, wc = (wid & 1) * 32, lq = lane >> 4, lm = lane & 15;
  int sidx = r * LDP + c8;
  for (int k0 = 0; k0 < HID; k0 += 32) {
    *(int4*)&sm[0 * PL + sidx] = *(const int4*)(a1 + aoff + k0);
    *(int4*)&sm[1 * PL + sidx] = *(const int4*)(a2 + aoff + k0);
    *(int4*)&sm[2 * PL + sidx] = *(const int4*)(a3 + aoff + k0);
    *(int4*)&sm[3 * PL + sidx] = *(const int4*)(b1 + boff + k0);
    *(int4*)&sm[4 * PL + sidx] = *(const int4*)(b2 + boff + k0);
    *(int4*)&sm[5 * PL + sidx] = *(const int4*)(b3 + boff + k0);
    __syncthreads();
    mfma_step6(sm, wr, wc, lm, lq, acc);
    __syncthreads();
  }
#pragma unroll
  for (int mt = 0; mt < 2; mt++)
#pragma unroll
    for (int nt = 0; nt < 2; nt++)
#pragma unroll
      for (int i = 0; i < 4; i++) {
        int gm = m0 + wr + mt * 16 + lq * 4 + i;
        int gc = n0 + wc + nt * 16 + lm;
        qkv[(size_t)gm * QKV_N + gc] = acc[mt][nt][i];
      }
}

__global__ __launch_bounds__(256) void gemm_scores6(
    const __bf16* __restrict__ qp1, const __bf16* __restrict__ qp2, const __bf16* __restrict__ qp3,
    const __bf16* __restrict__ kp1, const __bf16* __restrict__ kp2, const __bf16* __restrict__ kp3,
    __bf16* __restrict__ s1, __bf16* __restrict__ s2, __bf16* __restrict__ s3,
    int b, int h0) {
  int hz = blockIdx.z, h = h0 + hz;
  int m0 = blockIdx.x * 64, n0 = blockIdx.y * 64;
  size_t qbase = ((size_t)(b * NHEAD + h)) * SEQ * HDIM;
  size_t kbase = ((size_t)(b * NKV + (h >> 2))) * SEQ * HDIM;
  __shared__ __bf16 sm[6 * PL];
  int tid = threadIdx.x, r = tid >> 2, c8 = (tid & 3) * 8;
  size_t aoff = qbase + (size_t)(m0 + r) * HDIM + c8;
  size_t boff = kbase + (size_t)(n0 + r) * HDIM + c8;
  f32x4 acc[2][2] = {};
  int lane = tid & 63, wid = tid >> 6;
  int wr = (wid >> 1) * 32, wc = (wid & 1) * 32, lq = lane >> 4, lm = lane & 15;
  int sidx = r * LDP + c8;
  for (int k0 = 0; k0 < HDIM; k0 += 32) {
    *(int4*)&sm[0 * PL + sidx] = *(const int4*)(qp1 + aoff + k0);
    *(int4*)&sm[1 * PL + sidx] = *(const int4*)(qp2 + aoff + k0);
    *(int4*)&sm[2 * PL + sidx] = *(const int4*)(qp3 + aoff + k0);
    *(int4*)&sm[3 * PL + sidx] = *(const int4*)(kp1 + boff + k0);
    *(int4*)&sm[4 * PL + sidx] = *(const int4*)(kp2 + boff + k0);
    *(int4*)&sm[5 * PL + sidx] = *(const int4*)(kp3 + boff + k0);
    __syncthreads();
    mfma_step6(sm, wr, wc, lm, lq, acc);
    __syncthreads();
  }
#pragma unroll
  for (int mt = 0; mt < 2; mt++)
#pragma unroll
    for (int nt = 0; nt < 2; nt++)
#pragma unroll
      for (int i = 0; i < 4; i++) {
        int gm = m0 + wr + mt * 16 + lq * 4 + i;
        int gc = n0 + wc + nt * 16 + lm;
        size_t idx = ((size_t)hz * SEQ + gm) * SEQ + gc;
        __bf16 h1_, h2_, h3_;
        split3(acc[mt][nt][i] * 0.125f, h1_, h2_, h3_);
        s1[idx] = h1_; s2[idx] = h2_; s3[idx] = h3_;
      }
}

__global__ __launch_bounds__(256) void gemm_pv6(
    const __bf16* __restrict__ s1, const __bf16* __restrict__ s2, const __bf16* __restrict__ s3,
    const __bf16* __restrict__ vp1, const __bf16* __restrict__ vp2, const __bf16* __restrict__ vp3,
    __bf16* __restrict__ o1, __bf16* __restrict__ o2, __bf16* __restrict__ o3,
    int b, int h0) {
  int hz = blockIdx.z, h = h0 + hz;
  int m0 = blockIdx.x * 64;
  size_t pbase = (size_t)hz * SEQ * SEQ;
  size_t vbase = ((size_t)(b * NKV + (h >> 2))) * HDIM * SEQ;
  __shared__ __bf16 sm[6 * PL];
  int tid = threadIdx.x, r = tid >> 2, c8 = (tid & 3) * 8;
  size_t aoff = pbase + (size_t)(m0 + r) * SEQ + c8;
  size_t boff = vbase + (size_t)r * SEQ + c8;
  f32x4 acc[2][2] = {};
  int lane = tid & 63, wid = tid >> 6;
  int wr = (wid >> 1) * 32, wc = (wid & 1) * 32, lq = lane >> 4, lm = lane & 15;
  int sidx = r * LDP + c8;
  for (int k0 = 0; k0 < SEQ; k0 += 32) {
    *(int4*)&sm[0 * PL + sidx] = *(const int4*)(s1 + aoff + k0);
    *(int4*)&sm[1 * PL + sidx] = *(const int4*)(s2 + aoff + k0);
    *(int4*)&sm[2 * PL + sidx] = *(const int4*)(s3 + aoff + k0);
    *(int4*)&sm[3 * PL + sidx] = *(const int4*)(vp1 + boff + k0);
    *(int4*)&sm[4 * PL + sidx] = *(const int4*)(vp2 + boff + k0);
    *(int4*)&sm[5 * PL + sidx] = *(const int4*)(vp3 + boff + k0);
    __syncthreads();
    mfma_step6(sm, wr, wc, lm, lq, acc);
    __syncthreads();
  }
#pragma unroll
  for (int mt = 0; mt < 2; mt++)
#pragma unroll
    for (int nt = 0; nt < 2; nt++)
#pragma unroll
      for (int i = 0; i < 4; i++) {
        int gm = m0 + wr + mt * 16 + lq * 4 + i;
        int gc = wc + nt * 16 + lm;
        size_t idx = ((size_t)(b * SEQ + gm)) * HID + h * 64 + gc;
        __bf16 h1_, h2_, h3_;
        split3(acc[mt][nt][i], h1_, h2_, h3_);
        o1[idx] = h1_; o2[idx] = h2_; o3[idx] = h3_;
      }
}

__global__ __launch_bounds__(256) void gemm_oproj6(
    const __bf16* __restrict__ a1, const __bf16* __restrict__ a2, const __bf16* __restrict__ a3,
    const __bf16* __restrict__ b1, const __bf16* __restrict__ b2, const __bf16* __restrict__ b3,
    const float* __restrict__ hidden, float* __restrict__ x1, float* __restrict__ outp) {
  int m0 = blockIdx.x * 64, n0 = blockIdx.y * 64;
  __shared__ __bf16 sm[6 * PL];
  int tid = threadIdx.x, r = tid >> 2, c8 = (tid & 3) * 8;
  size_t aoff = (size_t)(m0 + r) * HID + c8, boff = (size_t)(n0 + r) * HID + c8;
  f32x4 acc[2][2] = {};
  int lane = tid & 63, wid = tid >> 6;
  int wr = (wid >> 1) * 32, wc = (wid & 1) * 32, lq = lane >> 4, lm = lane & 15;
  int sidx = r * LDP + c8;
  for (int k0 = 0; k0 < HID; k0 += 32) {
    *(int4*)&sm[0 * PL + sidx] = *(const int4*)(a1 + aoff + k0);
    *(int4*)&sm[1 * PL + sidx] = *(const int4*)(a2 + aoff + k0);
    *(int4*)&sm[2 * PL + sidx] = *(const int4*)(a3 + aoff + k0);
    *(int4*)&sm[3 * PL + sidx] = *(const int4*)(b1 + boff + k0);
    *(int4*)&sm[4 * PL + sidx] = *(const int4*)(b2 + boff + k0);
    *(int4*)&sm[5 * PL + sidx] = *(const int4*)(b3 + boff + k0);
    __syncthreads();
    mfma_step6(sm, wr, wc, lm, lq, acc);
    __syncthreads();
  }
#pragma unroll
  for (int mt = 0; mt < 2; mt++)
#pragma unroll
    for (int nt = 0; nt < 2; nt++)
#pragma unroll
      for (int i = 0; i < 4; i++) {
        int gm = m0 + wr + mt * 16 + lq * 4 + i;
        int gc = n0 + wc + nt * 16 + lm;
        size_t idx = (size_t)gm * HID + gc;
        float val = hidden[idx] + acc[mt][nt][i];
        x1[idx] = val;
        outp[idx] = val;
      }
}

// ---------------- MoE ----------------

__global__ void zero_cnt_kernel(int* cnt) {
  if (threadIdx.x < NEXP) cnt[threadIdx.x] = 0;
}

__global__ __launch_bounds__(64) void gating_kernel(
    const float* __restrict__ h2f, const float* __restrict__ gw,
    float* __restrict__ logits_out, int* __restrict__ cnt,
    int* __restrict__ list, float* __restrict__ wt) {
  int t = blockIdx.x;
  int lane = threadIdx.x;
  const float* xr = h2f + (size_t)t * HID;
  float part[NEXP] = {};
  for (int k = lane; k < HID; k += 64) {
    float xv = xr[k];
#pragma unroll
    for (int e = 0; e < NEXP; e++) part[e] += xv * gw[e * HID + k];
  }
#pragma unroll
  for (int e = 0; e < NEXP; e++)
    for (int off = 32; off; off >>= 1) part[e] += __shfl_xor(part[e], off);
  if (lane < NEXP) logits_out[(size_t)t * NEXP + lane] = part[lane];
  float mx = part[0];
#pragma unroll
  for (int e = 1; e < NEXP; e++) mx = fmaxf(mx, part[e]);
  float pe[NEXP];
#pragma unroll
  for (int e = 0; e < NEXP; e++) pe[e] = expf(part[e] - mx);
  int e0 = 0; float p0 = pe[0];
#pragma unroll
  for (int e = 1; e < NEXP; e++) if (pe[e] > p0) { p0 = pe[e]; e0 = e; }
  int e1 = -1; float p1 = -1.f;
#pragma unroll
  for (int e = 0; e < NEXP; e++) if (e != e0 && pe[e] > p1) { p1 = pe[e]; e1 = e; }
  float wsum = p0 + p1;
  if (lane == 0) {
    int pos0 = atomicAdd(&cnt[e0], 1);
    list[e0 * TOK + pos0] = t;
    wt[e0 * TOK + pos0] = p0 / wsum;
    int pos1 = atomicAdd(&cnt[e1], 1);
    list[e1 * TOK + pos1] = t;
    wt[e1 * TOK + pos1] = p1 / wsum;
  }
}

__global__ void scan_kernel(const int* __restrict__ cnt, int* __restrict__ base) {
  if (threadIdx.x == 0 && blockIdx.x == 0) {
    int acc = 0;
    for (int e = 0; e < NEXP; e++) { base[e] = acc; acc += cnt[e]; }
    base[NEXP] = acc;
  }
}

// fused gate+up, 64x64 tile, BK=32, LDS double-buffer + reg prefetch, 1 barrier/iter.
// grid (FFD/64, TOK/64, NEXP) — N-dim FASTEST so active blocks cover all 8 XCDs.
__global__ __launch_bounds__(256) void gemm_gateup3(
    const __bf16* __restrict__ h2, const float* __restrict__ w_gate,
    const float* __restrict__ w_up, const int* __restrict__ cnt,
    const int* __restrict__ base, const int* __restrict__ list,
    __bf16* __restrict__ aws) {
  int e = blockIdx.z;
  int ce = cnt[e];
  int m0 = blockIdx.y * 64;
  if (m0 >= ce) return;
  int n0 = blockIdx.x * 64;
  int be = base[e];
  __shared__ __bf16 As[2][PL], Bg[2][PL], Bu[2][PL];  // 30 KB
  int tid = threadIdx.x, r = tid >> 2, c8 = (tid & 3) * 8;
  int ridx = m0 + r; if (ridx >= ce) ridx = ce - 1;
  const __bf16* arow = h2 + (size_t)list[e * TOK + ridx] * HID + c8;
  const float* bgrow = w_gate + ((size_t)e * FFD + n0 + r) * HID + c8;
  const float* burow = w_up + ((size_t)e * FFD + n0 + r) * HID + c8;
  int lane = tid & 63, wid = tid >> 6;
  int wr = (wid >> 1) * 32, wc = (wid & 1) * 32, lq = lane >> 4, lm = lane & 15;
  int sidx = r * LDP + c8;
  f32x4 ag[2][2] = {}, au[2][2] = {};
  int4 ra; float4 rg0, rg1, ru0, ru1;
  auto preload = [&](int k0) {
    ra = *(const int4*)(arow + k0);
    rg0 = *(const float4*)(bgrow + k0);
    rg1 = *(const float4*)(bgrow + k0 + 4);
    ru0 = *(const float4*)(burow + k0);
    ru1 = *(const float4*)(burow + k0 + 4);
  };
  auto stage = [&](int p) {
    *(int4*)&As[p][sidx] = ra;
    cvt8(&Bg[p][sidx], rg0, rg1);
    cvt8(&Bu[p][sidx], ru0, ru1);
  };
  preload(0);
  stage(0);
  preload(32);
  __syncthreads();
  int p = 0;
  for (int k0 = 0; k0 < HID; k0 += 32, p ^= 1) {
    bf16x8 a0 = *(const bf16x8*)(&As[p][(wr + lm) * LDP + lq * 8]);
    bf16x8 a1 = *(const bf16x8*)(&As[p][(wr + 16 + lm) * LDP + lq * 8]);
    bf16x8 g0 = *(const bf16x8*)(&Bg[p][(wc + lm) * LDP + lq * 8]);
    bf16x8 g1 = *(const bf16x8*)(&Bg[p][(wc + 16 + lm) * LDP + lq * 8]);
    bf16x8 u0 = *(const bf16x8*)(&Bu[p][(wc + lm) * LDP + lq * 8]);
    bf16x8 u1 = *(const bf16x8*)(&Bu[p][(wc + 16 + lm) * LDP + lq * 8]);
    if (k0 + 32 < HID) {
      stage(p ^ 1);
      preload(k0 + 64 < HID ? k0 + 64 : 0);
    }
    ag[0][0] = __builtin_amdgcn_mfma_f32_16x16x32_bf16(a0, g0, ag[0][0], 0, 0, 0);
    ag[0][1] = __builtin_amdgcn_mfma_f32_16x16x32_bf16(a0, g1, ag[0][1], 0, 0, 0);
    ag[1][0] = __builtin_amdgcn_mfma_f32_16x16x32_bf16(a1, g0, ag[1][0], 0, 0, 0);
    ag[1][1] = __builtin_amdgcn_mfma_f32_16x16x32_bf16(a1, g1, ag[1][1], 0, 0, 0);
    au[0][0] = __builtin_amdgcn_mfma_f32_16x16x32_bf16(a0, u0, au[0][0], 0, 0, 0);
    au[0][1] = __builtin_amdgcn_mfma_f32_16x16x32_bf16(a0, u1, au[0][1], 0, 0, 0);
    au[1][0] = __builtin_amdgcn_mfma_f32_16x16x32_bf16(a1, u0, au[1][0], 0, 0, 0);
    au[1][1] = __builtin_amdgcn_mfma_f32_16x16x32_bf16(a1, u1, au[1][1], 0, 0, 0);
    __syncthreads();
  }
#pragma unroll
  for (int mt = 0; mt < 2; mt++)
#pragma unroll
    for (int nt = 0; nt < 2; nt++)
#pragma unroll
      for (int i = 0; i < 4; i++) {
        int lrow = m0 + wr + mt * 16 + lq * 4 + i;
        if (lrow < ce) {
          int gc = n0 + wc + nt * 16 + lm;
          float g = ag[mt][nt][i], u = au[mt][nt][i];
          float a = g / (1.0f + expf(-g)) * u;
          aws[((size_t)(be + lrow)) * FFD + gc] = (__bf16)a;
        }
      }
}

// down GEMM, 64x64, dbuf + reg prefetch; weighted atomic scatter.
// grid (HID/64, TOK/64, NEXP) — N-dim fastest (all XCDs).
__global__ __launch_bounds__(256) void gemm_down3(
    const __bf16* __restrict__ aws, const float* __restrict__ w_down,
    const int* __restrict__ cnt, const int* __restrict__ base,
    const int* __restrict__ list, const float* __restrict__ wt,
    float* __restrict__ outp) {
  int e = blockIdx.z;
  int ce = cnt[e];
  int m0 = blockIdx.y * 64;
  if (m0 >= ce) return;
  int n0 = blockIdx.x * 64;
  int be = base[e];
  __shared__ __bf16 As[2][PL], Bs[2][PL];  // 20 KB
  int tid = threadIdx.x, r = tid >> 2, c8 = (tid & 3) * 8;
  int ridx = m0 + r; if (ridx >= ce) ridx = ce - 1;
  const __bf16* arow = aws + (size_t)(be + ridx) * FFD + c8;
  const float* brow = w_down + ((size_t)e * HID + n0 + r) * FFD + c8;
  int lane = tid & 63, wid = tid >> 6;
  int wr = (wid >> 1) * 32, wc = (wid & 1) * 32, lq = lane >> 4, lm = lane & 15;
  int sidx = r * LDP + c8;
  f32x4 acc[2][2] = {};
  int4 ra; float4 rb0, rb1;
  auto preload = [&](int k0) {
    ra = *(const int4*)(arow + k0);
    rb0 = *(const float4*)(brow + k0);
    rb1 = *(const float4*)(brow + k0 + 4);
  };
  auto stage = [&](int p) {
    *(int4*)&As[p][sidx] = ra;
    cvt8(&Bs[p][sidx], rb0, rb1);
  };
  preload(0);
  stage(0);
  preload(32);
  __syncthreads();
  int p = 0;
  for (int k0 = 0; k0 < FFD; k0 += 32, p ^= 1) {
    bf16x8 a0 = *(const bf16x8*)(&As[p][(wr + lm) * LDP + lq * 8]);
    bf16x8 a1 = *(const bf16x8*)(&As[p][(wr + 16 + lm) * LDP + lq * 8]);
    bf16x8 b0 = *(const bf16x8*)(&Bs[p][(wc + lm) * LDP + lq * 8]);
    bf16x8 b1 = *(const bf16x8*)(&Bs[p][(wc + 16 + lm) * LDP + lq * 8]);
    if (k0 + 32 < FFD) {
      stage(p ^ 1);
      preload(k0 + 64 < FFD ? k0 + 64 : 0);
    }
    acc[0][0] = __builtin_amdgcn_mfma_f32_16x16x32_bf16(a0, b0, acc[0][0], 0, 0, 0);
    acc[0][1] = __builtin_amdgcn_mfma_f32_16x16x32_bf16(a0, b1, acc[0][1], 0, 0, 0);
    acc[1][0] = __builtin_amdgcn_mfma_f32_16x16x32_bf16(a1, b0, acc[1][0], 0, 0, 0);
    acc[1][1] = __builtin_amdgcn_mfma_f32_16x16x32_bf16(a1, b1, acc[1][1], 0, 0, 0);
    __syncthreads();
  }
#pragma unroll
  for (int mt = 0; mt < 2; mt++)
#pragma unroll
    for (int nt = 0; nt < 2; nt++)
#pragma unroll
      for (int i = 0; i < 4; i++) {
        int lrow = m0 + wr + mt * 16 + lq * 4 + i;
        if (lrow < ce) {
          int gc = n0 + wc + nt * 16 + lm;
          int tok = list[e * TOK + lrow];
          float wgt = wt[e * TOK + lrow];
          atomicAdd(&outp[(size_t)tok * HID + gc], wgt * acc[mt][nt][i]);
        }
      }
}

// ---------------- launcher ----------------

extern "C" void kernel_launch(void* const* d_in, const int* in_sizes, int n_in,
                              void* d_out, int out_size, void* d_ws, size_t ws_size,
                              hipStream_t stream) {
  const float* hidden = (const float*)d_in[0];
  const int* pos_ids = (const int*)d_in[1];
  const float* ln1_w = (const float*)d_in[2];
  const float* ln2_w = (const float*)d_in[3];
  const float* q_w = (const float*)d_in[4];
  const float* k_w = (const float*)d_in[5];
  const float* v_w = (const float*)d_in[6];
  const float* o_w = (const float*)d_in[7];
  const float* qn_w = (const float*)d_in[8];
  const float* kn_w = (const float*)d_in[9];
  const float* gate_w = (const float*)d_in[10];
  const float* w_gate = (const float*)d_in[11];
  const float* w_up = (const float*)d_in[12];
  const float* w_down = (const float*)d_in[13];
  float* outp = (float*)d_out;
  float* logits_out = outp + (size_t)TOK * HID;

  char* ws = (char*)d_ws;
  size_t off = 0;
  auto alloc = [&](size_t bytes) {
    void* p = ws + off;
    off += (bytes + 255) & ~(size_t)255;
    return p;
  };
  const size_t NWQ = (size_t)QKV_N * HID, NOW = (size_t)HID * HID;
  __bf16* wqp1 = (__bf16*)alloc(NWQ * 2); __bf16* wqp2 = (__bf16*)alloc(NWQ * 2);
  __bf16* wqp3 = (__bf16*)alloc(NWQ * 2);
  __bf16* owp1 = (__bf16*)alloc(NOW * 2); __bf16* owp2 = (__bf16*)alloc(NOW * 2);
  __bf16* owp3 = (__bf16*)alloc(NOW * 2);
  const size_t NH1 = (size_t)TOK * HID;
  __bf16* h1p1 = (__bf16*)alloc(NH1 * 2); __bf16* h1p2 = (__bf16*)alloc(NH1 * 2);
  __bf16* h1p3 = (__bf16*)alloc(NH1 * 2);
  float* qkvf = (float*)alloc((size_t)TOK * QKV_N * 4);
  const size_t NQ = (size_t)NB * NHEAD * SEQ * HDIM, NK = (size_t)NB * NKV * SEQ * HDIM;
  __bf16* qp1 = (__bf16*)alloc(NQ * 2); __bf16* qp2 = (__bf16*)alloc(NQ * 2);
  __bf16* qp3 = (__bf16*)alloc(NQ * 2);
  __bf16* kp1 = (__bf16*)alloc(NK * 2); __bf16* kp2 = (__bf16*)alloc(NK * 2);
  __bf16* kp3 = (__bf16*)alloc(NK * 2);
  __bf16* vp1 = (__bf16*)alloc(NK * 2); __bf16* vp2 = (__bf16*)alloc(NK * 2);
  __bf16* vp3 = (__bf16*)alloc(NK * 2);
  // everything before the score planes is ~110 MB; pick HCH by what remains.
  size_t fixed_rest = (NH1 * 2) * 3 + NH1 * 4 * 2 + NH1 * 2 + NEXP * 4 * 2 +
                      (size_t)NEXP * TOK * 8 + (size_t)TOK * 2 * FFD * 2 + (1 << 20);
  size_t avail = (ws_size > off + fixed_rest) ? (ws_size - off - fixed_rest) : 0;
  int hch = (avail >= (size_t)16 * SEQ * SEQ * 2 * 3) ? 16 : 8;
  const size_t NP = (size_t)hch * SEQ * SEQ;
  __bf16* sp1 = (__bf16*)alloc(NP * 2); __bf16* sp2 = (__bf16*)alloc(NP * 2);
  __bf16* sp3 = (__bf16*)alloc(NP * 2);
  __bf16* op1 = (__bf16*)alloc(NH1 * 2); __bf16* op2 = (__bf16*)alloc(NH1 * 2);
  __bf16* op3 = (__bf16*)alloc(NH1 * 2);
  float* x1 = (float*)alloc(NH1 * 4);
  float* h2f = (float*)alloc(NH1 * 4);
  __bf16* h2b = (__bf16*)alloc(NH1 * 2);
  int* cnt = (int*)alloc(NEXP * 4);
  int* base = (int*)alloc((NEXP + 1) * 4);
  int* list = (int*)alloc((size_t)NEXP * TOK * 4);
  float* wt = (float*)alloc((size_t)NEXP * TOK * 4);
  __bf16* aws = (__bf16*)alloc((size_t)TOK * 2 * FFD * 2);
  (void)in_sizes; (void)n_in; (void)out_size;

  // weight splits
  split3_kernel<<<1024, 256, 0, stream>>>(q_w, wqp1, wqp2, wqp3, 1024 * 1024);
  split3_kernel<<<256, 256, 0, stream>>>(k_w, wqp1 + 1024 * 1024, wqp2 + 1024 * 1024,
                                         wqp3 + 1024 * 1024, 256 * 1024);
  split3_kernel<<<256, 256, 0, stream>>>(v_w, wqp1 + 1280 * 1024, wqp2 + 1280 * 1024,
                                         wqp3 + 1280 * 1024, 256 * 1024);
  split3_kernel<<<1024, 256, 0, stream>>>(o_w, owp1, owp2, owp3, 1024 * 1024);

  // attention (fp32-grade via triple-split MFMA)
  rmsnorm_split3_kernel<<<TOK, 256, 0, stream>>>(hidden, ln1_w, h1p1, h1p2, h1p3);
  gemm_qkv6<<<dim3(TOK / 64, QKV_N / 64), 256, 0, stream>>>(
      h1p1, h1p2, h1p3, wqp1, wqp2, wqp3, qkvf);
  rope_split_kernel<<<TOK, 256, 0, stream>>>(qkvf, pos_ids, qn_w, kn_w,
                                             qp1, qp2, qp3, kp1, kp2, kp3, vp1, vp2, vp3);
  for (int b = 0; b < NB; b++)
    for (int hc = 0; hc < NHEAD / hch; hc++) {
      int h0 = hc * hch;
      gemm_scores6<<<dim3(SEQ / 64, SEQ / 64, hch), 256, 0, stream>>>(
          qp1, qp2, qp3, kp1, kp2, kp3, sp1, sp2, sp3, b, h0);
      softmax3_kernel<<<hch * SEQ, 256, 0, stream>>>(sp1, sp2, sp3);
      gemm_pv6<<<dim3(SEQ / 64, 1, hch), 256, 0, stream>>>(
          sp1, sp2, sp3, vp1, vp2, vp3, op1, op2, op3, b, h0);
    }
  gemm_oproj6<<<dim3(TOK / 64, HID / 64), 256, 0, stream>>>(
      op1, op2, op3, owp1, owp2, owp3, hidden, x1, outp);

  // MoE
  rmsnorm_dual_kernel<<<TOK, 256, 0, stream>>>(x1, ln2_w, h2f, h2b);
  zero_cnt_kernel<<<1, 64, 0, stream>>>(cnt);
  gating_kernel<<<TOK, 64, 0, stream>>>(h2f, gate_w, logits_out, cnt, list, wt);
  scan_kernel<<<1, 1, 0, stream>>>(cnt, base);
  gemm_gateup3<<<dim3(FFD / 64, TOK / 64, NEXP), 256, 0, stream>>>(
      h2b, w_gate, w_up, cnt, base, list, aws);
  gemm_down3<<<dim3(HID / 64, TOK / 64, NEXP), 256, 0, stream>>>(
      aws, w_down, cnt, base, list, wt, outp);
}